// Round 8
// baseline (1578.830 us; speedup 1.0000x reference)
//
#include <hip/hip_runtime.h>

#define D_MODEL 1024
#define NUM_HEADS 16
#define D_HEAD 64
#define BATCH 2
#define SEQ 2048
#define MTOT (BATCH * SEQ) /* 4096 */
#define PLANE ((size_t)MTOT * D_MODEL)
#define QSCALE 0.1803368801f /* 0.125 * log2(e) : folds 1/sqrt(dh) and exp->exp2 */

typedef unsigned short us;
typedef __bf16 bf16x8 __attribute__((ext_vector_type(8)));
typedef float floatx4 __attribute__((ext_vector_type(4)));

// ---------- bf16 helpers ----------
__device__ __forceinline__ unsigned int f2bf(float f) {
  union { float f; unsigned int i; } v; v.f = f;
  unsigned int r = v.i + 0x7FFFu + ((v.i >> 16) & 1u); // RNE
  return r >> 16;
}
__device__ __forceinline__ us f2bf_trunc(float f) {
  union { float f; unsigned int i; } v; v.f = f;
  return (us)(v.i >> 16);
}

// ---------- fused f32 -> bf16 conversion: x, Wq, Wk, Wv in one launch ----------
__global__ __launch_bounds__(256) void convert_all(const float* __restrict__ x,
                                                   const float* __restrict__ Wq,
                                                   const float* __restrict__ Wk,
                                                   const float* __restrict__ Wv,
                                                   us* __restrict__ xbf,
                                                   us* __restrict__ Wqkv) {
  const int i = blockIdx.x * 256 + threadIdx.x;  // float4 index
  const float* src;
  us* dst;
  if (i < (1 << 20)) {  // x: 4M elems = 1M float4
    src = x + (size_t)i * 4;
    dst = xbf + (size_t)i * 4;
  } else {
    const int j = i - (1 << 20);
    const int w = j >> 18;                // 0..2 (each W = 256K float4)
    const int o = j & ((1 << 18) - 1);
    const float* ws = (w == 0) ? Wq : (w == 1) ? Wk : Wv;
    src = ws + (size_t)o * 4;
    dst = Wqkv + (size_t)w * (D_MODEL * D_MODEL) + (size_t)o * 4;
  }
  float4 v = *(const float4*)src;
  uint2 pk;
  pk.x = f2bf(v.x) | (f2bf(v.y) << 16);
  pk.y = f2bf(v.z) | (f2bf(v.w) << 16);
  *(uint2*)dst = pk;
}

// ---------- single-tensor f32 -> bf16 (Wo, post-attention) ----------
__global__ __launch_bounds__(256) void convert_bf16(const float* __restrict__ src,
                                                    us* __restrict__ dst, int n4) {
  int i = blockIdx.x * 256 + threadIdx.x;
  if (i >= n4) return;
  float4 v = *(const float4*)(src + (size_t)i * 4);
  uint2 pk;
  pk.x = f2bf(v.x) | (f2bf(v.y) << 16);
  pk.y = f2bf(v.z) | (f2bf(v.w) << 16);
  *(uint2*)(dst + (size_t)i * 4) = pk;
}

// ---------- MFMA GEMM: C(M,N) = A(M,K) * B(N,K)^T, bf16 inputs, fp32 acc ----------
// CMODE 1 (fused QKV, N=3072): plane0 -> Q*QSCALE, plane1 -> K, plane2 -> V
// written TRANSPOSED as Vt[b][h][d][s]. CMODE 2: f32 out.
template <int CMODE>
__global__ __launch_bounds__(256) void gemm_mfma(const us* __restrict__ A,
                                                 const us* __restrict__ B,
                                                 void* __restrict__ Cv,
                                                 int M, int N, int K) {
  __shared__ __bf16 As[128 * 32];
  __shared__ __bf16 Bs[128 * 32];
  const int tid = threadIdx.x;
  const int wid = tid >> 6;
  const int lane = tid & 63;
  const int bm = blockIdx.y * 128;
  const int bn = blockIdx.x * 128;
  const int wm = (wid & 1) * 64;
  const int wn = (wid >> 1) * 64;
  const int lr = lane & 15;
  const int quad = lane >> 4;

  floatx4 acc[4][4] = {};
  const int cb0 = wid * 128;

  for (int k0 = 0; k0 < K; k0 += 32) {
    __syncthreads();
#pragma unroll
    for (int p = 0; p < 2; ++p) {
      const int cb = cb0 + p * 64;
      const int c = cb + lane;
      const us* ga = A + (size_t)(bm + (c >> 2)) * K + (k0 + (c & 3) * 8);
      const us* gb = B + (size_t)(bn + (c >> 2)) * K + (k0 + (c & 3) * 8);
      __builtin_amdgcn_global_load_lds((const __attribute__((address_space(1))) void*)ga,
                                       (__attribute__((address_space(3))) void*)(&As[cb * 8]),
                                       16, 0, 0);
      __builtin_amdgcn_global_load_lds((const __attribute__((address_space(1))) void*)gb,
                                       (__attribute__((address_space(3))) void*)(&Bs[cb * 8]),
                                       16, 0, 0);
    }
    __syncthreads();

    bf16x8 a[4], b[4];
#pragma unroll
    for (int i = 0; i < 4; ++i)
      a[i] = *(const bf16x8*)&As[(wm + i * 16 + lr) * 32 + quad * 8];
#pragma unroll
    for (int j = 0; j < 4; ++j)
      b[j] = *(const bf16x8*)&Bs[(wn + j * 16 + lr) * 32 + quad * 8];
#pragma unroll
    for (int i = 0; i < 4; ++i)
#pragma unroll
      for (int j = 0; j < 4; ++j)
        acc[i][j] = __builtin_amdgcn_mfma_f32_16x16x32_bf16(a[i], b[j], acc[i][j], 0, 0, 0);
  }

  // C/D layout: col = lane&15, row = quad*4 + reg (verified r3/r4/r6)
#pragma unroll
  for (int i = 0; i < 4; ++i) {
#pragma unroll
    for (int j = 0; j < 4; ++j) {
      const int col = bn + wn + j * 16 + lr;
      if constexpr (CMODE == 1) {
        us* dst = (us*)Cv;
        const int plane = col >> 10;
        if (plane < 2) {
          const float s = (plane == 0) ? QSCALE : 1.0f;
#pragma unroll
          for (int r = 0; r < 4; ++r) {
            const int row = bm + wm + i * 16 + quad * 4 + r;
            dst[(size_t)plane * PLANE + (size_t)row * 1024 + (col & 1023)] =
                (us)f2bf(acc[i][j][r] * s);
          }
        } else {
          // V transposed: Vt[((b*16+h)*64+d)*2048 + s]; r-consecutive => s-consecutive
          const int d = col & 63;
          const int hh = (col >> 6) & 15;
          const int row0 = bm + wm + i * 16 + quad * 4;
          const int bb = row0 >> 11;
          const int ss = row0 & 2047;
          uint2 pk;
          pk.x = f2bf(acc[i][j][0]) | (f2bf(acc[i][j][1]) << 16);
          pk.y = f2bf(acc[i][j][2]) | (f2bf(acc[i][j][3]) << 16);
          *(uint2*)&dst[2 * PLANE + ((size_t)((bb * 16 + hh) * 64 + d)) * 2048 + ss] = pk;
        }
      } else {
#pragma unroll
        for (int r = 0; r < 4; ++r) {
          const int row = bm + wm + i * 16 + quad * 4 + r;
          ((float*)Cv)[(size_t)row * N + col] = acc[i][j][r];
        }
      }
    }
  }
}

// ---------- MFMA causal flash attention ----------
// 512 blocks x 4 waves x 32 q-rows (128-row strips). Blocks n and n+256 get
// complementary strips (s, 15-s) -> near-constant work per CU at 2 blocks/CU.
// K/V fragment reads hoisted: both 16-row groups of a wave share kb/vb frags.
// Fixed-base exp2 softmax (Q pre-scaled by QSCALE in GEMM), l via MFMA-ones,
// Vt pre-transposed in GEMM epilogue, register-prefetched staging.
#define ASTR 72 /* us per LDS row: conflict-free b128 frag reads */

__global__ __launch_bounds__(256, 2) void attn_mfma(const us* __restrict__ Qb,
                                                    const us* __restrict__ Kb,
                                                    const us* __restrict__ Vtg,
                                                    us* __restrict__ Ob) {
  const int bx = blockIdx.x;
  const int b = bx >> 8;
  const int idx = bx & 255;
  const int h = idx >> 4;
  const int s0 = idx & 15;
  const int strip = b ? (15 - s0) : s0;  // pair (n, n+256): strips sum to 15
  const int q0 = strip * 128;
  const int ntiles = 2 * strip + 2;
  const int tid = threadIdx.x;
  const int w = tid >> 6;
  const int lane = tid & 63;
  const int lr = lane & 15;
  const int quad = lane >> 4;

  __shared__ us Ks[64 * ASTR];       // K tile [key][dim]
  __shared__ us Vs[64 * ASTR];       // V tile [dim][key] (pre-transposed global)
  __shared__ us Ps[4 * 16 * ASTR];   // per-wave P scratch [qrow][key]

  // Q A-frags for this wave's 2 groups of 16 rows: A[m=lr][k=quad*8+j]
  bf16x8 qa[2][2];
#pragma unroll
  for (int g = 0; g < 2; ++g) {
    const us* qp = Qb + (size_t)(b * SEQ + q0 + w * 32 + g * 16 + lr) * D_MODEL + h * D_HEAD;
    qa[g][0] = *(const bf16x8*)(qp + quad * 8);
    qa[g][1] = *(const bf16x8*)(qp + 32 + quad * 8);
  }

  floatx4 oacc[2][4] = {};           // [g][nt]: rows quad*4+r, dim nt*16+lr
  floatx4 lacc[2] = {};
  bf16x8 ones;
#pragma unroll
  for (int i = 0; i < 8; ++i) ones[i] = (__bf16)1.0f;

  const us* kbase = Kb + (size_t)(b * SEQ) * D_MODEL + h * D_HEAD;
  const us* vbase = Vtg + (size_t)((b * 16 + h) * 64) * 2048;
  us* const pg = &Ps[w * 16 * ASTR];

  // prefetch tile 0 (per thread: 2x uint4 K + 2x uint4 V)
  uint4 kreg[2], vreg[2];
#pragma unroll
  for (int p = 0; p < 2; ++p) {
    const int c = tid + 256 * p;  // row = c>>3, chunk = c&7
    kreg[p] = *(const uint4*)(kbase + (size_t)(c >> 3) * D_MODEL + (c & 7) * 8);
    vreg[p] = *(const uint4*)(vbase + (size_t)(c >> 3) * 2048 + (c & 7) * 8);
  }

  for (int t = 0; t < ntiles; ++t) {
    const int k0 = t * 64;
    __syncthreads();
#pragma unroll
    for (int p = 0; p < 2; ++p) {
      const int c = tid + 256 * p;
      *(uint4*)&Ks[(c >> 3) * ASTR + (c & 7) * 8] = kreg[p];
      *(uint4*)&Vs[(c >> 3) * ASTR + (c & 7) * 8] = vreg[p];
    }
    __syncthreads();
    if (t + 1 < ntiles) {
      const int kn = k0 + 64;
#pragma unroll
      for (int p = 0; p < 2; ++p) {
        const int c = tid + 256 * p;
        kreg[p] = *(const uint4*)(kbase + (size_t)(kn + (c >> 3)) * D_MODEL + (c & 7) * 8);
        vreg[p] = *(const uint4*)(vbase + (size_t)(c >> 3) * 2048 + kn + (c & 7) * 8);
      }
    }

    // hoisted fragment reads: shared by both q-groups of this wave
    bf16x8 kb[4][2], vb[4][2];
#pragma unroll
    for (int jt = 0; jt < 4; ++jt) {
      kb[jt][0] = *(const bf16x8*)&Ks[(jt * 16 + lr) * ASTR + quad * 8];
      kb[jt][1] = *(const bf16x8*)&Ks[(jt * 16 + lr) * ASTR + 32 + quad * 8];
      vb[jt][0] = *(const bf16x8*)&Vs[(jt * 16 + lr) * ASTR + quad * 8];
      vb[jt][1] = *(const bf16x8*)&Vs[(jt * 16 + lr) * ASTR + 32 + quad * 8];
    }

#pragma unroll
    for (int g = 0; g < 2; ++g) {
      const int grow = q0 + w * 32 + g * 16;      // first q-row of this group
      if (k0 > grow + 15) continue;               // wave-uniform skip
      int jtmax = ((grow + 15 - k0) >> 4) + 1;
      if (jtmax > 4) jtmax = 4;

      // zero-fill the P chunk that is read (via pa0/pa1) but not computed
      if ((jtmax == 1 || jtmax == 3) && lane < 32) {
        *(uint4*)&pg[(lane >> 1) * ASTR + jtmax * 16 + (lane & 1) * 8] =
            make_uint4(0, 0, 0, 0);
      }

      for (int jt = 0; jt < jtmax; ++jt) {        // wave-uniform trip count
        floatx4 s = {};
        s = __builtin_amdgcn_mfma_f32_16x16x32_bf16(qa[g][0], kb[jt][0], s, 0, 0, 0);
        s = __builtin_amdgcn_mfma_f32_16x16x32_bf16(qa[g][1], kb[jt][1], s, 0, 0, 0);
        const bool needMask = (k0 + jt * 16 + 15 > grow);
#pragma unroll
        for (int r = 0; r < 4; ++r) {
          float p = __builtin_amdgcn_exp2f(s[r]);
          if (needMask && (k0 + jt * 16 + lr > grow + quad * 4 + r)) p = 0.f;
          pg[(quad * 4 + r) * ASTR + jt * 16 + lr] = f2bf_trunc(p);
        }
      }

      // P A-frags (keys 0..31 / 32..63); same-wave DS ordering => visible
      const bf16x8 pa0 = *(const bf16x8*)&pg[lr * ASTR + quad * 8];
      lacc[g] = __builtin_amdgcn_mfma_f32_16x16x32_bf16(pa0, ones, lacc[g], 0, 0, 0);
#pragma unroll
      for (int nt = 0; nt < 4; ++nt)
        oacc[g][nt] = __builtin_amdgcn_mfma_f32_16x16x32_bf16(pa0, vb[nt][0], oacc[g][nt], 0, 0, 0);
      if (jtmax >= 3) {  // keys 32..63 have any unmasked element
        const bf16x8 pa1 = *(const bf16x8*)&pg[lr * ASTR + 32 + quad * 8];
        lacc[g] = __builtin_amdgcn_mfma_f32_16x16x32_bf16(pa1, ones, lacc[g], 0, 0, 0);
#pragma unroll
        for (int nt = 0; nt < 4; ++nt)
          oacc[g][nt] = __builtin_amdgcn_mfma_f32_16x16x32_bf16(pa1, vb[nt][1], oacc[g][nt], 0, 0, 0);
      }
    }
  }

  // ---- epilogue: per wave-group, O/l -> pg transpose -> coalesced 16B stores ----
#pragma unroll
  for (int g = 0; g < 2; ++g) {
    const int grow = q0 + w * 32 + g * 16;
    float inv[4];
#pragma unroll
    for (int r = 0; r < 4; ++r) inv[r] = 1.f / lacc[g][r];
#pragma unroll
    for (int nt = 0; nt < 4; ++nt)
#pragma unroll
      for (int r = 0; r < 4; ++r)
        pg[(quad * 4 + r) * ASTR + nt * 16 + lr] = f2bf_trunc(oacc[g][nt][r] * inv[r]);
#pragma unroll
    for (int p = 0; p < 2; ++p) {
      const int c = lane + 64 * p;  // row = c>>3 (0..15), chunk = c&7
      *(uint4*)(Ob + (size_t)(b * SEQ + grow + (c >> 3)) * D_MODEL + h * D_HEAD + (c & 7) * 8) =
          *(const uint4*)&pg[(c >> 3) * ASTR + (c & 7) * 8];
    }
  }
}

extern "C" void kernel_launch(void* const* d_in, const int* in_sizes, int n_in,
                              void* d_out, int out_size, void* d_ws, size_t ws_size,
                              hipStream_t stream) {
  const float* x  = (const float*)d_in[0];
  const float* Wq = (const float*)d_in[1];
  const float* Wk = (const float*)d_in[2];
  const float* Wv = (const float*)d_in[3];
  const float* Wo = (const float*)d_in[4];

  // ws (32 MB): [x_bf | Qb | Kb | Vt]; Ab aliases x_bf (x dead after QKV GEMM).
  us* xbf = (us*)d_ws;
  us* Qb  = xbf + PLANE;
  us* Kb  = xbf + 2 * PLANE;
  us* Vt  = xbf + 3 * PLANE;  // Vt[b][h][d][s], 8 MB
  us* Ab  = xbf;
  // d_out (16 MB f32) doubles as scratch for fused Wqkv_bf (6 MB) until final GEMM.
  us* Wqkv = (us*)d_out;
  us* Wobf = Qb;  // Qb slot dead after attention
  float* out = (float*)d_out;

  const int WN = D_MODEL * D_MODEL;

  convert_all<<<7168, 256, 0, stream>>>(x, Wq, Wk, Wv, xbf, Wqkv);

  gemm_mfma<1><<<dim3(3072 / 128, MTOT / 128), 256, 0, stream>>>(xbf, Wqkv, Qb, MTOT, 3072, D_MODEL);

  attn_mfma<<<512, 256, 0, stream>>>(Qb, Kb, Vt, Ab);

  convert_bf16<<<WN / 4 / 256, 256, 0, stream>>>(Wo, Wobf, WN / 4);
  gemm_mfma<2><<<dim3(D_MODEL / 128, MTOT / 128), 256, 0, stream>>>(Ab, Wobf, out, MTOT, D_MODEL, D_MODEL);
}

// Round 9
// 221.966 us; speedup vs baseline: 7.1129x; 7.1129x over previous
//
#include <hip/hip_runtime.h>

#define D_MODEL 1024
#define NUM_HEADS 16
#define D_HEAD 64
#define BATCH 2
#define SEQ 2048
#define MTOT (BATCH * SEQ) /* 4096 */
#define PLANE ((size_t)MTOT * D_MODEL)
#define QSCALE 0.1803368801f /* 0.125 * log2(e) : folds 1/sqrt(dh) and exp->exp2 */

typedef unsigned short us;
typedef __bf16 bf16x8 __attribute__((ext_vector_type(8)));
typedef float floatx4 __attribute__((ext_vector_type(4)));

// ---------- bf16 helpers ----------
__device__ __forceinline__ unsigned int f2bf(float f) {
  union { float f; unsigned int i; } v; v.f = f;
  unsigned int r = v.i + 0x7FFFu + ((v.i >> 16) & 1u); // RNE
  return r >> 16;
}
__device__ __forceinline__ unsigned int f2bf_tr(float f) {
  union { float f; unsigned int i; } v; v.f = f;
  return v.i >> 16;
}

// ---------- fused f32 -> bf16 conversion: x, Wq, Wk, Wv in one launch ----------
__global__ __launch_bounds__(256) void convert_all(const float* __restrict__ x,
                                                   const float* __restrict__ Wq,
                                                   const float* __restrict__ Wk,
                                                   const float* __restrict__ Wv,
                                                   us* __restrict__ xbf,
                                                   us* __restrict__ Wqkv) {
  const int i = blockIdx.x * 256 + threadIdx.x;  // float4 index
  const float* src;
  us* dst;
  if (i < (1 << 20)) {  // x: 4M elems = 1M float4
    src = x + (size_t)i * 4;
    dst = xbf + (size_t)i * 4;
  } else {
    const int j = i - (1 << 20);
    const int w = j >> 18;                // 0..2 (each W = 256K float4)
    const int o = j & ((1 << 18) - 1);
    const float* ws = (w == 0) ? Wq : (w == 1) ? Wk : Wv;
    src = ws + (size_t)o * 4;
    dst = Wqkv + (size_t)w * (D_MODEL * D_MODEL) + (size_t)o * 4;
  }
  float4 v = *(const float4*)src;
  uint2 pk;
  pk.x = f2bf(v.x) | (f2bf(v.y) << 16);
  pk.y = f2bf(v.z) | (f2bf(v.w) << 16);
  *(uint2*)dst = pk;
}

// ---------- single-tensor f32 -> bf16 (Wo, post-attention) ----------
__global__ __launch_bounds__(256) void convert_bf16(const float* __restrict__ src,
                                                    us* __restrict__ dst, int n4) {
  int i = blockIdx.x * 256 + threadIdx.x;
  if (i >= n4) return;
  float4 v = *(const float4*)(src + (size_t)i * 4);
  uint2 pk;
  pk.x = f2bf(v.x) | (f2bf(v.y) << 16);
  pk.y = f2bf(v.z) | (f2bf(v.w) << 16);
  *(uint2*)(dst + (size_t)i * 4) = pk;
}

// ---------- MFMA GEMM: C(M,N) = A(M,K) * B(N,K)^T, bf16 inputs, fp32 acc ----------
// CMODE 1 (fused QKV, N=3072): plane0 -> Q*QSCALE, plane1 -> K, plane2 -> V
// written TRANSPOSED as Vt[b][h][d][s]. CMODE 2: f32 out.
template <int CMODE>
__global__ __launch_bounds__(256) void gemm_mfma(const us* __restrict__ A,
                                                 const us* __restrict__ B,
                                                 void* __restrict__ Cv,
                                                 int M, int N, int K) {
  __shared__ __bf16 As[128 * 32];
  __shared__ __bf16 Bs[128 * 32];
  const int tid = threadIdx.x;
  const int wid = tid >> 6;
  const int lane = tid & 63;
  const int bm = blockIdx.y * 128;
  const int bn = blockIdx.x * 128;
  const int wm = (wid & 1) * 64;
  const int wn = (wid >> 1) * 64;
  const int lr = lane & 15;
  const int quad = lane >> 4;

  floatx4 acc[4][4] = {};
  const int cb0 = wid * 128;

  for (int k0 = 0; k0 < K; k0 += 32) {
    __syncthreads();
#pragma unroll
    for (int p = 0; p < 2; ++p) {
      const int cb = cb0 + p * 64;
      const int c = cb + lane;
      const us* ga = A + (size_t)(bm + (c >> 2)) * K + (k0 + (c & 3) * 8);
      const us* gb = B + (size_t)(bn + (c >> 2)) * K + (k0 + (c & 3) * 8);
      __builtin_amdgcn_global_load_lds((const __attribute__((address_space(1))) void*)ga,
                                       (__attribute__((address_space(3))) void*)(&As[cb * 8]),
                                       16, 0, 0);
      __builtin_amdgcn_global_load_lds((const __attribute__((address_space(1))) void*)gb,
                                       (__attribute__((address_space(3))) void*)(&Bs[cb * 8]),
                                       16, 0, 0);
    }
    __syncthreads();

    bf16x8 a[4], b[4];
#pragma unroll
    for (int i = 0; i < 4; ++i)
      a[i] = *(const bf16x8*)&As[(wm + i * 16 + lr) * 32 + quad * 8];
#pragma unroll
    for (int j = 0; j < 4; ++j)
      b[j] = *(const bf16x8*)&Bs[(wn + j * 16 + lr) * 32 + quad * 8];
#pragma unroll
    for (int i = 0; i < 4; ++i)
#pragma unroll
      for (int j = 0; j < 4; ++j)
        acc[i][j] = __builtin_amdgcn_mfma_f32_16x16x32_bf16(a[i], b[j], acc[i][j], 0, 0, 0);
  }

  // C/D layout: col = lane&15, row = quad*4 + reg (verified r3/r4/r6)
#pragma unroll
  for (int i = 0; i < 4; ++i) {
#pragma unroll
    for (int j = 0; j < 4; ++j) {
      const int col = bn + wn + j * 16 + lr;
      if constexpr (CMODE == 1) {
        us* dst = (us*)Cv;
        const int plane = col >> 10;
        if (plane < 2) {
          const float s = (plane == 0) ? QSCALE : 1.0f;
#pragma unroll
          for (int r = 0; r < 4; ++r) {
            const int row = bm + wm + i * 16 + quad * 4 + r;
            dst[(size_t)plane * PLANE + (size_t)row * 1024 + (col & 1023)] =
                (us)f2bf(acc[i][j][r] * s);
          }
        } else {
          // V transposed: Vt[((b*16+h)*64+d)*2048 + s]; r-consecutive => s-consecutive
          const int d = col & 63;
          const int hh = (col >> 6) & 15;
          const int row0 = bm + wm + i * 16 + quad * 4;
          const int bb = row0 >> 11;
          const int ss = row0 & 2047;
          uint2 pk;
          pk.x = f2bf(acc[i][j][0]) | (f2bf(acc[i][j][1]) << 16);
          pk.y = f2bf(acc[i][j][2]) | (f2bf(acc[i][j][3]) << 16);
          *(uint2*)&dst[2 * PLANE + ((size_t)((bb * 16 + hh) * 64 + d)) * 2048 + ss] = pk;
        }
      } else {
#pragma unroll
        for (int r = 0; r < 4; ++r) {
          const int row = bm + wm + i * 16 + quad * 4 + r;
          ((float*)Cv)[(size_t)row * N + col] = acc[i][j][r];
        }
      }
    }
  }
}

// ---------- MFMA causal flash attention (transposed-score formulation) ----------
// 512 blocks x 4 waves x 32 q-rows (2 groups of 16). Blocks bx / bx+256 get
// complementary strips (s, 15-s). All loops statically unrolled; no dynamic
// register-array indexing (r8 lesson: runtime-indexed reg arrays => spill).
// S^T = mfma(K,Q): lane holds key=quad*4+r (row), qrow=lr (col) => the 4 P
// values per lane are LDS-consecutive => ds_write_b64. P layout [qrow][key]
// unchanged => PV B-frags identical. O^T = mfma(Vt,P), l^T = mfma(ones,P);
// epilogue likewise b64. Fixed-base exp2 softmax (Q pre-scaled by QSCALE).
#define ASTR 72 /* us per LDS row */

__global__ __launch_bounds__(256, 2) void attn_mfma(const us* __restrict__ Qb,
                                                    const us* __restrict__ Kb,
                                                    const us* __restrict__ Vtg,
                                                    us* __restrict__ Ob) {
  const int bx = blockIdx.x;
  const int b = bx >> 8;
  const int idx = bx & 255;
  const int h = idx >> 4;
  const int s0 = idx & 15;
  const int strip = b ? (15 - s0) : s0;  // pair (n, n+256): strips sum to 15
  const int q0 = strip * 128;
  const int ntiles = 2 * strip + 2;
  const int tid = threadIdx.x;
  const int w = tid >> 6;
  const int lane = tid & 63;
  const int lr = lane & 15;
  const int quad = lane >> 4;

  __shared__ us Ks[64 * ASTR];        // K tile [key][dim]
  __shared__ us Vs[64 * ASTR];        // V tile [dim][key] (pre-transposed)
  __shared__ us Ps[8 * 16 * ASTR];    // per (wave,group) P [qrow][key]

  // Q frags (used as MFMA B-operand: n=qrow=lr, k=quad*8+j)
  bf16x8 qa[2][2];
#pragma unroll
  for (int g = 0; g < 2; ++g) {
    const us* qp = Qb + (size_t)(b * SEQ + q0 + w * 32 + g * 16 + lr) * D_MODEL + h * D_HEAD;
    qa[g][0] = *(const bf16x8*)(qp + quad * 8);
    qa[g][1] = *(const bf16x8*)(qp + 32 + quad * 8);
  }

  floatx4 oacc[2][4] = {};  // [g][nt]: O^T — rows dim=nt*16+quad*4+r, col qrow=lr
  floatx4 lacc[2] = {};     // l^T — col qrow=lr (rows identical)
  bf16x8 ones;
#pragma unroll
  for (int i = 0; i < 8; ++i) ones[i] = (__bf16)1.0f;

  const us* kbase = Kb + (size_t)(b * SEQ) * D_MODEL + h * D_HEAD;
  const us* vbase = Vtg + (size_t)((b * 16 + h) * 64) * 2048;
  us* const pg0 = &Ps[(w * 2 + 0) * 16 * ASTR];
  us* const pg1 = &Ps[(w * 2 + 1) * 16 * ASTR];

  // prefetch tile 0
  uint4 kreg[2], vreg[2];
#pragma unroll
  for (int p = 0; p < 2; ++p) {
    const int c = tid + 256 * p;  // row = c>>3, chunk = c&7
    kreg[p] = *(const uint4*)(kbase + (size_t)(c >> 3) * D_MODEL + (c & 7) * 8);
    vreg[p] = *(const uint4*)(vbase + (size_t)(c >> 3) * 2048 + (c & 7) * 8);
  }

  for (int t = 0; t < ntiles; ++t) {
    const int k0 = t * 64;
    __syncthreads();
#pragma unroll
    for (int p = 0; p < 2; ++p) {
      const int c = tid + 256 * p;
      *(uint4*)&Ks[(c >> 3) * ASTR + (c & 7) * 8] = kreg[p];
      *(uint4*)&Vs[(c >> 3) * ASTR + (c & 7) * 8] = vreg[p];
    }
    __syncthreads();
    if (t + 1 < ntiles) {
      const int kn = k0 + 64;
#pragma unroll
      for (int p = 0; p < 2; ++p) {
        const int c = tid + 256 * p;
        kreg[p] = *(const uint4*)(kbase + (size_t)(kn + (c >> 3)) * D_MODEL + (c & 7) * 8);
        vreg[p] = *(const uint4*)(vbase + (size_t)(c >> 3) * 2048 + kn + (c & 7) * 8);
      }
    }

    // ---- S^T = K Q^T per 16-key block; exp2; b64 P-writes ----
#pragma unroll
    for (int jt = 0; jt < 4; ++jt) {
      const bf16x8 kb0 = *(const bf16x8*)&Ks[(jt * 16 + lr) * ASTR + quad * 8];
      const bf16x8 kb1 = *(const bf16x8*)&Ks[(jt * 16 + lr) * ASTR + 32 + quad * 8];
#pragma unroll
      for (int g = 0; g < 2; ++g) {
        floatx4 s = {};
        s = __builtin_amdgcn_mfma_f32_16x16x32_bf16(kb0, qa[g][0], s, 0, 0, 0);
        s = __builtin_amdgcn_mfma_f32_16x16x32_bf16(kb1, qa[g][1], s, 0, 0, 0);
        const int grow = q0 + w * 32 + g * 16;   // qrow = grow + lr
        const int kb = k0 + jt * 16 + quad * 4;  // key  = kb + r
        const bool needMask = (k0 + jt * 16 + 15 > grow);
        float p[4];
#pragma unroll
        for (int r = 0; r < 4; ++r) {
          float e = __builtin_amdgcn_exp2f(s[r]);
          if (needMask && (kb + r > grow + lr)) e = 0.f;
          p[r] = e;
        }
        uint2 pk;
        pk.x = f2bf_tr(p[0]) | (f2bf_tr(p[1]) << 16);
        pk.y = f2bf_tr(p[2]) | (f2bf_tr(p[3]) << 16);
        us* const pg = g ? pg1 : pg0;
        *(uint2*)&pg[lr * ASTR + jt * 16 + quad * 4] = pk;
      }
    }

    // ---- P B-frags; l^T and O^T accumulate ----
    const bf16x8 pa00 = *(const bf16x8*)&pg0[lr * ASTR + quad * 8];
    const bf16x8 pa01 = *(const bf16x8*)&pg0[lr * ASTR + 32 + quad * 8];
    const bf16x8 pa10 = *(const bf16x8*)&pg1[lr * ASTR + quad * 8];
    const bf16x8 pa11 = *(const bf16x8*)&pg1[lr * ASTR + 32 + quad * 8];
    lacc[0] = __builtin_amdgcn_mfma_f32_16x16x32_bf16(ones, pa00, lacc[0], 0, 0, 0);
    lacc[0] = __builtin_amdgcn_mfma_f32_16x16x32_bf16(ones, pa01, lacc[0], 0, 0, 0);
    lacc[1] = __builtin_amdgcn_mfma_f32_16x16x32_bf16(ones, pa10, lacc[1], 0, 0, 0);
    lacc[1] = __builtin_amdgcn_mfma_f32_16x16x32_bf16(ones, pa11, lacc[1], 0, 0, 0);
#pragma unroll
    for (int nt = 0; nt < 4; ++nt) {
      const bf16x8 vb0 = *(const bf16x8*)&Vs[(nt * 16 + lr) * ASTR + quad * 8];
      const bf16x8 vb1 = *(const bf16x8*)&Vs[(nt * 16 + lr) * ASTR + 32 + quad * 8];
      oacc[0][nt] = __builtin_amdgcn_mfma_f32_16x16x32_bf16(vb0, pa00, oacc[0][nt], 0, 0, 0);
      oacc[0][nt] = __builtin_amdgcn_mfma_f32_16x16x32_bf16(vb1, pa01, oacc[0][nt], 0, 0, 0);
      oacc[1][nt] = __builtin_amdgcn_mfma_f32_16x16x32_bf16(vb0, pa10, oacc[1][nt], 0, 0, 0);
      oacc[1][nt] = __builtin_amdgcn_mfma_f32_16x16x32_bf16(vb1, pa11, oacc[1][nt], 0, 0, 0);
    }
  }

  // ---- epilogue: O^T/l -> pg as [qrow][dim] (b64 writes) -> 16B stores ----
#pragma unroll
  for (int g = 0; g < 2; ++g) {
    us* const pg = g ? pg1 : pg0;
    const int grow = q0 + w * 32 + g * 16;
    const float inv = 1.f / lacc[g][0];  // all 4 regs equal (l^T rows identical)
#pragma unroll
    for (int nt = 0; nt < 4; ++nt) {
      uint2 pk;
      pk.x = f2bf_tr(oacc[g][nt][0] * inv) | (f2bf_tr(oacc[g][nt][1] * inv) << 16);
      pk.y = f2bf_tr(oacc[g][nt][2] * inv) | (f2bf_tr(oacc[g][nt][3] * inv) << 16);
      *(uint2*)&pg[lr * ASTR + nt * 16 + quad * 4] = pk;
    }
#pragma unroll
    for (int p = 0; p < 2; ++p) {
      const int c = lane + 64 * p;  // row = c>>3 (0..15), chunk = c&7
      *(uint4*)(Ob + (size_t)(b * SEQ + grow + (c >> 3)) * D_MODEL + h * D_HEAD + (c & 7) * 8) =
          *(const uint4*)&pg[(c >> 3) * ASTR + (c & 7) * 8];
    }
  }
}

extern "C" void kernel_launch(void* const* d_in, const int* in_sizes, int n_in,
                              void* d_out, int out_size, void* d_ws, size_t ws_size,
                              hipStream_t stream) {
  const float* x  = (const float*)d_in[0];
  const float* Wq = (const float*)d_in[1];
  const float* Wk = (const float*)d_in[2];
  const float* Wv = (const float*)d_in[3];
  const float* Wo = (const float*)d_in[4];

  // ws (32 MB): [x_bf | Qb | Kb | Vt]; Ab aliases x_bf (x dead after QKV GEMM).
  us* xbf = (us*)d_ws;
  us* Qb  = xbf + PLANE;
  us* Kb  = xbf + 2 * PLANE;
  us* Vt  = xbf + 3 * PLANE;  // Vt[b][h][d][s], 8 MB
  us* Ab  = xbf;
  // d_out (16 MB f32) doubles as scratch for fused Wqkv_bf (6 MB) until final GEMM.
  us* Wqkv = (us*)d_out;
  us* Wobf = Qb;  // Qb slot dead after attention
  float* out = (float*)d_out;

  const int WN = D_MODEL * D_MODEL;

  convert_all<<<7168, 256, 0, stream>>>(x, Wq, Wk, Wv, xbf, Wqkv);

  gemm_mfma<1><<<dim3(3072 / 128, MTOT / 128), 256, 0, stream>>>(xbf, Wqkv, Qb, MTOT, 3072, D_MODEL);

  attn_mfma<<<512, 256, 0, stream>>>(Qb, Kb, Vt, Ab);

  convert_bf16<<<WN / 4 / 256, 256, 0, stream>>>(Wo, Wobf, WN / 4);
  gemm_mfma<2><<<dim3(D_MODEL / 128, MTOT / 128), 256, 0, stream>>>(Ab, Wobf, out, MTOT, D_MODEL, D_MODEL);
}

// Round 10
// 196.546 us; speedup vs baseline: 8.0329x; 1.1293x over previous
//
#include <hip/hip_runtime.h>

#define D_MODEL 1024
#define NUM_HEADS 16
#define D_HEAD 64
#define BATCH 2
#define SEQ 2048
#define MTOT (BATCH * SEQ) /* 4096 */
#define PLANE ((size_t)MTOT * D_MODEL)
#define QSCALE 0.1803368801f /* 0.125 * log2(e) : folds 1/sqrt(dh) and exp->exp2 */

typedef unsigned short us;
typedef __bf16 bf16x8 __attribute__((ext_vector_type(8)));
typedef float floatx4 __attribute__((ext_vector_type(4)));

// ---------- bf16 helpers ----------
__device__ __forceinline__ unsigned int f2bf(float f) {
  union { float f; unsigned int i; } v; v.f = f;
  unsigned int r = v.i + 0x7FFFu + ((v.i >> 16) & 1u); // RNE
  return r >> 16;
}
__device__ __forceinline__ unsigned int f2bf_tr(float f) {
  union { float f; unsigned int i; } v; v.f = f;
  return v.i >> 16;
}

// ---------- fused f32 -> bf16 conversion: x, Wq, Wk, Wv in one launch ----------
__global__ __launch_bounds__(256) void convert_all(const float* __restrict__ x,
                                                   const float* __restrict__ Wq,
                                                   const float* __restrict__ Wk,
                                                   const float* __restrict__ Wv,
                                                   us* __restrict__ xbf,
                                                   us* __restrict__ Wqkv) {
  const int i = blockIdx.x * 256 + threadIdx.x;  // float4 index
  const float* src;
  us* dst;
  if (i < (1 << 20)) {  // x: 4M elems = 1M float4
    src = x + (size_t)i * 4;
    dst = xbf + (size_t)i * 4;
  } else {
    const int j = i - (1 << 20);
    const int w = j >> 18;                // 0..2 (each W = 256K float4)
    const int o = j & ((1 << 18) - 1);
    const float* ws = (w == 0) ? Wq : (w == 1) ? Wk : Wv;
    src = ws + (size_t)o * 4;
    dst = Wqkv + (size_t)w * (D_MODEL * D_MODEL) + (size_t)o * 4;
  }
  float4 v = *(const float4*)src;
  uint2 pk;
  pk.x = f2bf(v.x) | (f2bf(v.y) << 16);
  pk.y = f2bf(v.z) | (f2bf(v.w) << 16);
  *(uint2*)dst = pk;
}

// ---------- single-tensor f32 -> bf16 (Wo, post-attention) ----------
__global__ __launch_bounds__(256) void convert_bf16(const float* __restrict__ src,
                                                    us* __restrict__ dst, int n4) {
  int i = blockIdx.x * 256 + threadIdx.x;
  if (i >= n4) return;
  float4 v = *(const float4*)(src + (size_t)i * 4);
  uint2 pk;
  pk.x = f2bf(v.x) | (f2bf(v.y) << 16);
  pk.y = f2bf(v.z) | (f2bf(v.w) << 16);
  *(uint2*)(dst + (size_t)i * 4) = pk;
}

// ---------- MFMA GEMM: C(M,N) = A(M,K) * B(N,K)^T, bf16 inputs, fp32 acc ----------
// CMODE 1 (fused QKV, N=3072): plane0 -> Q*QSCALE, plane1 -> K, plane2 -> V
// written TRANSPOSED as Vt[b][h][d][s]. CMODE 2: f32 out.
template <int CMODE>
__global__ __launch_bounds__(256) void gemm_mfma(const us* __restrict__ A,
                                                 const us* __restrict__ B,
                                                 void* __restrict__ Cv,
                                                 int M, int N, int K) {
  __shared__ __bf16 As[128 * 32];
  __shared__ __bf16 Bs[128 * 32];
  const int tid = threadIdx.x;
  const int wid = tid >> 6;
  const int lane = tid & 63;
  const int bm = blockIdx.y * 128;
  const int bn = blockIdx.x * 128;
  const int wm = (wid & 1) * 64;
  const int wn = (wid >> 1) * 64;
  const int lr = lane & 15;
  const int quad = lane >> 4;

  floatx4 acc[4][4] = {};
  const int cb0 = wid * 128;

  for (int k0 = 0; k0 < K; k0 += 32) {
    __syncthreads();
#pragma unroll
    for (int p = 0; p < 2; ++p) {
      const int cb = cb0 + p * 64;
      const int c = cb + lane;
      const us* ga = A + (size_t)(bm + (c >> 2)) * K + (k0 + (c & 3) * 8);
      const us* gb = B + (size_t)(bn + (c >> 2)) * K + (k0 + (c & 3) * 8);
      __builtin_amdgcn_global_load_lds((const __attribute__((address_space(1))) void*)ga,
                                       (__attribute__((address_space(3))) void*)(&As[cb * 8]),
                                       16, 0, 0);
      __builtin_amdgcn_global_load_lds((const __attribute__((address_space(1))) void*)gb,
                                       (__attribute__((address_space(3))) void*)(&Bs[cb * 8]),
                                       16, 0, 0);
    }
    __syncthreads();

    bf16x8 a[4], b[4];
#pragma unroll
    for (int i = 0; i < 4; ++i)
      a[i] = *(const bf16x8*)&As[(wm + i * 16 + lr) * 32 + quad * 8];
#pragma unroll
    for (int j = 0; j < 4; ++j)
      b[j] = *(const bf16x8*)&Bs[(wn + j * 16 + lr) * 32 + quad * 8];
#pragma unroll
    for (int i = 0; i < 4; ++i)
#pragma unroll
      for (int j = 0; j < 4; ++j)
        acc[i][j] = __builtin_amdgcn_mfma_f32_16x16x32_bf16(a[i], b[j], acc[i][j], 0, 0, 0);
  }

  // C/D layout: col = lane&15, row = quad*4 + reg (verified r3/r4/r6)
#pragma unroll
  for (int i = 0; i < 4; ++i) {
#pragma unroll
    for (int j = 0; j < 4; ++j) {
      const int col = bn + wn + j * 16 + lr;
      if constexpr (CMODE == 1) {
        us* dst = (us*)Cv;
        const int plane = col >> 10;
        if (plane < 2) {
          const float s = (plane == 0) ? QSCALE : 1.0f;
#pragma unroll
          for (int r = 0; r < 4; ++r) {
            const int row = bm + wm + i * 16 + quad * 4 + r;
            dst[(size_t)plane * PLANE + (size_t)row * 1024 + (col & 1023)] =
                (us)f2bf(acc[i][j][r] * s);
          }
        } else {
          // V transposed: Vt[((b*16+h)*64+d)*2048 + s]; r-consecutive => s-consecutive
          const int d = col & 63;
          const int hh = (col >> 6) & 15;
          const int row0 = bm + wm + i * 16 + quad * 4;
          const int bb = row0 >> 11;
          const int ss = row0 & 2047;
          uint2 pk;
          pk.x = f2bf(acc[i][j][0]) | (f2bf(acc[i][j][1]) << 16);
          pk.y = f2bf(acc[i][j][2]) | (f2bf(acc[i][j][3]) << 16);
          *(uint2*)&dst[2 * PLANE + ((size_t)((bb * 16 + hh) * 64 + d)) * 2048 + ss] = pk;
        }
      } else {
#pragma unroll
        for (int r = 0; r < 4; ++r) {
          const int row = bm + wm + i * 16 + quad * 4 + r;
          ((float*)Cv)[(size_t)row * N + col] = acc[i][j][r];
        }
      }
    }
  }
}

// ---------- MFMA causal flash attention (transposed scores, LDS dbuf) ----------
// 512 blocks x 4 waves x 32 q-rows (2 groups of 16). Blocks bx / bx+256 get
// complementary strips (s, 15-s). Double-buffered K/V staging: ONE barrier per
// tile; t+1 global loads issued before compute(t), ds_writes after, so the
// s_waitcnt vmcnt lands late and staging overlaps compute. P-buffer is
// wave-private (same-wave DS ordering; no barrier). All loops statically
// unrolled; no runtime-indexed register arrays (r8 lesson).
// S^T = mfma(K,Q): key=quad*4+r (row), qrow=lr (col) => 4 P values/lane are
// LDS-consecutive => b64 writes. O^T = mfma(Vt,P), l^T = mfma(ones,P).
#define ASTR 72 /* us per LDS row */

__global__ __launch_bounds__(256, 2) void attn_mfma(const us* __restrict__ Qb,
                                                    const us* __restrict__ Kb,
                                                    const us* __restrict__ Vtg,
                                                    us* __restrict__ Ob) {
  const int bx = blockIdx.x;
  const int b = bx >> 8;
  const int idx = bx & 255;
  const int h = idx >> 4;
  const int s0 = idx & 15;
  const int strip = b ? (15 - s0) : s0;  // pair (n, n+256): strips sum to 15
  const int q0 = strip * 128;
  const int ntiles = 2 * strip + 2;
  const int tid = threadIdx.x;
  const int w = tid >> 6;
  const int lane = tid & 63;
  const int lr = lane & 15;
  const int quad = lane >> 4;

  __shared__ us Ks[2][64 * ASTR];     // K tile [key][dim], double-buffered
  __shared__ us Vs[2][64 * ASTR];     // V tile [dim][key] (pre-transposed)
  __shared__ us Ps[8 * 16 * ASTR];    // per (wave,group) P [qrow][key]

  // Q frags (used as MFMA B-operand: n=qrow=lr, k=quad*8+j)
  bf16x8 qa[2][2];
#pragma unroll
  for (int g = 0; g < 2; ++g) {
    const us* qp = Qb + (size_t)(b * SEQ + q0 + w * 32 + g * 16 + lr) * D_MODEL + h * D_HEAD;
    qa[g][0] = *(const bf16x8*)(qp + quad * 8);
    qa[g][1] = *(const bf16x8*)(qp + 32 + quad * 8);
  }

  floatx4 oacc[2][4] = {};  // [g][nt]: O^T — rows dim=nt*16+quad*4+r, col qrow=lr
  floatx4 lacc[2] = {};     // l^T — col qrow=lr (rows identical)
  bf16x8 ones;
#pragma unroll
  for (int i = 0; i < 8; ++i) ones[i] = (__bf16)1.0f;

  const us* kbase = Kb + (size_t)(b * SEQ) * D_MODEL + h * D_HEAD;
  const us* vbase = Vtg + (size_t)((b * 16 + h) * 64) * 2048;
  us* const pg0 = &Ps[(w * 2 + 0) * 16 * ASTR];
  us* const pg1 = &Ps[(w * 2 + 1) * 16 * ASTR];

  // prologue: tile 0 -> regs -> LDS buf 0 -> barrier
  uint4 kreg[2], vreg[2];
#pragma unroll
  for (int p = 0; p < 2; ++p) {
    const int c = tid + 256 * p;  // row = c>>3, chunk = c&7
    kreg[p] = *(const uint4*)(kbase + (size_t)(c >> 3) * D_MODEL + (c & 7) * 8);
    vreg[p] = *(const uint4*)(vbase + (size_t)(c >> 3) * 2048 + (c & 7) * 8);
  }
#pragma unroll
  for (int p = 0; p < 2; ++p) {
    const int c = tid + 256 * p;
    *(uint4*)&Ks[0][(c >> 3) * ASTR + (c & 7) * 8] = kreg[p];
    *(uint4*)&Vs[0][(c >> 3) * ASTR + (c & 7) * 8] = vreg[p];
  }
  __syncthreads();

  for (int t = 0; t < ntiles; ++t) {
    const int k0 = t * 64;
    const int cur = t & 1;
    const bool more = (t + 1 < ntiles);

    // issue t+1 global loads first: latency hidden behind compute(t)
    if (more) {
      const int kn = k0 + 64;
#pragma unroll
      for (int p = 0; p < 2; ++p) {
        const int c = tid + 256 * p;
        kreg[p] = *(const uint4*)(kbase + (size_t)(kn + (c >> 3)) * D_MODEL + (c & 7) * 8);
        vreg[p] = *(const uint4*)(vbase + (size_t)(c >> 3) * 2048 + kn + (c & 7) * 8);
      }
    }

    // ---- S^T = K Q^T per 16-key block; exp2; b64 P-writes ----
#pragma unroll
    for (int jt = 0; jt < 4; ++jt) {
      const bf16x8 kb0 = *(const bf16x8*)&Ks[cur][(jt * 16 + lr) * ASTR + quad * 8];
      const bf16x8 kb1 = *(const bf16x8*)&Ks[cur][(jt * 16 + lr) * ASTR + 32 + quad * 8];
#pragma unroll
      for (int g = 0; g < 2; ++g) {
        floatx4 s = {};
        s = __builtin_amdgcn_mfma_f32_16x16x32_bf16(kb0, qa[g][0], s, 0, 0, 0);
        s = __builtin_amdgcn_mfma_f32_16x16x32_bf16(kb1, qa[g][1], s, 0, 0, 0);
        const int grow = q0 + w * 32 + g * 16;   // qrow = grow + lr
        const int kb = k0 + jt * 16 + quad * 4;  // key  = kb + r
        const bool needMask = (k0 + jt * 16 + 15 > grow);
        float p[4];
#pragma unroll
        for (int r = 0; r < 4; ++r) {
          float e = __builtin_amdgcn_exp2f(s[r]);
          if (needMask && (kb + r > grow + lr)) e = 0.f;
          p[r] = e;
        }
        uint2 pk;
        pk.x = f2bf_tr(p[0]) | (f2bf_tr(p[1]) << 16);
        pk.y = f2bf_tr(p[2]) | (f2bf_tr(p[3]) << 16);
        us* const pg = g ? pg1 : pg0;
        *(uint2*)&pg[lr * ASTR + jt * 16 + quad * 4] = pk;
      }
    }

    // ---- P B-frags; l^T and O^T accumulate ----
    const bf16x8 pa00 = *(const bf16x8*)&pg0[lr * ASTR + quad * 8];
    const bf16x8 pa01 = *(const bf16x8*)&pg0[lr * ASTR + 32 + quad * 8];
    const bf16x8 pa10 = *(const bf16x8*)&pg1[lr * ASTR + quad * 8];
    const bf16x8 pa11 = *(const bf16x8*)&pg1[lr * ASTR + 32 + quad * 8];
    lacc[0] = __builtin_amdgcn_mfma_f32_16x16x32_bf16(ones, pa00, lacc[0], 0, 0, 0);
    lacc[0] = __builtin_amdgcn_mfma_f32_16x16x32_bf16(ones, pa01, lacc[0], 0, 0, 0);
    lacc[1] = __builtin_amdgcn_mfma_f32_16x16x32_bf16(ones, pa10, lacc[1], 0, 0, 0);
    lacc[1] = __builtin_amdgcn_mfma_f32_16x16x32_bf16(ones, pa11, lacc[1], 0, 0, 0);
#pragma unroll
    for (int nt = 0; nt < 4; ++nt) {
      const bf16x8 vb0 = *(const bf16x8*)&Vs[cur][(nt * 16 + lr) * ASTR + quad * 8];
      const bf16x8 vb1 = *(const bf16x8*)&Vs[cur][(nt * 16 + lr) * ASTR + 32 + quad * 8];
      oacc[0][nt] = __builtin_amdgcn_mfma_f32_16x16x32_bf16(vb0, pa00, oacc[0][nt], 0, 0, 0);
      oacc[0][nt] = __builtin_amdgcn_mfma_f32_16x16x32_bf16(vb1, pa01, oacc[0][nt], 0, 0, 0);
      oacc[1][nt] = __builtin_amdgcn_mfma_f32_16x16x32_bf16(vb0, pa10, oacc[1][nt], 0, 0, 0);
      oacc[1][nt] = __builtin_amdgcn_mfma_f32_16x16x32_bf16(vb1, pa11, oacc[1][nt], 0, 0, 0);
    }

    // ---- write t+1 into the other buffer; single barrier ----
    if (more) {
      const int nxt = cur ^ 1;
#pragma unroll
      for (int p = 0; p < 2; ++p) {
        const int c = tid + 256 * p;
        *(uint4*)&Ks[nxt][(c >> 3) * ASTR + (c & 7) * 8] = kreg[p];
        *(uint4*)&Vs[nxt][(c >> 3) * ASTR + (c & 7) * 8] = vreg[p];
      }
    }
    __syncthreads();
  }

  // ---- epilogue: O^T/l -> pg as [qrow][dim] (b64 writes) -> 16B stores ----
#pragma unroll
  for (int g = 0; g < 2; ++g) {
    us* const pg = g ? pg1 : pg0;
    const int grow = q0 + w * 32 + g * 16;
    const float inv = 1.f / lacc[g][0];  // all 4 regs equal (l^T rows identical)
#pragma unroll
    for (int nt = 0; nt < 4; ++nt) {
      uint2 pk;
      pk.x = f2bf_tr(oacc[g][nt][0] * inv) | (f2bf_tr(oacc[g][nt][1] * inv) << 16);
      pk.y = f2bf_tr(oacc[g][nt][2] * inv) | (f2bf_tr(oacc[g][nt][3] * inv) << 16);
      *(uint2*)&pg[lr * ASTR + nt * 16 + quad * 4] = pk;
    }
#pragma unroll
    for (int p = 0; p < 2; ++p) {
      const int c = lane + 64 * p;  // row = c>>3 (0..15), chunk = c&7
      *(uint4*)(Ob + (size_t)(b * SEQ + grow + (c >> 3)) * D_MODEL + h * D_HEAD + (c & 7) * 8) =
          *(const uint4*)&pg[(c >> 3) * ASTR + (c & 7) * 8];
    }
  }
}

extern "C" void kernel_launch(void* const* d_in, const int* in_sizes, int n_in,
                              void* d_out, int out_size, void* d_ws, size_t ws_size,
                              hipStream_t stream) {
  const float* x  = (const float*)d_in[0];
  const float* Wq = (const float*)d_in[1];
  const float* Wk = (const float*)d_in[2];
  const float* Wv = (const float*)d_in[3];
  const float* Wo = (const float*)d_in[4];

  // ws (32 MB): [x_bf | Qb | Kb | Vt]; Ab aliases x_bf (x dead after QKV GEMM).
  us* xbf = (us*)d_ws;
  us* Qb  = xbf + PLANE;
  us* Kb  = xbf + 2 * PLANE;
  us* Vt  = xbf + 3 * PLANE;  // Vt[b][h][d][s], 8 MB
  us* Ab  = xbf;
  // d_out (16 MB f32) doubles as scratch for fused Wqkv_bf (6 MB) until final GEMM.
  us* Wqkv = (us*)d_out;
  us* Wobf = Qb;  // Qb slot dead after attention
  float* out = (float*)d_out;

  const int WN = D_MODEL * D_MODEL;

  convert_all<<<7168, 256, 0, stream>>>(x, Wq, Wk, Wv, xbf, Wqkv);

  gemm_mfma<1><<<dim3(3072 / 128, MTOT / 128), 256, 0, stream>>>(xbf, Wqkv, Qb, MTOT, 3072, D_MODEL);

  attn_mfma<<<512, 256, 0, stream>>>(Qb, Kb, Vt, Ab);

  convert_bf16<<<WN / 4 / 256, 256, 0, stream>>>(Wo, Wobf, WN / 4);
  gemm_mfma<2><<<dim3(D_MODEL / 128, MTOT / 128), 256, 0, stream>>>(Ab, Wobf, out, MTOT, D_MODEL, D_MODEL);
}